// Round 9
// baseline (91.710 us; speedup 1.0000x reference)
//
#include <hip/hip_runtime.h>

#define NV 1084
#define NPART 64   // precompute partials

// ws layout (floats):
//  [0, B*192)            A_rel [B][16][12]
//  next NPART*1392       Mpart[p]: M[21][16][4] (1344) + jt[48]
//  next 1344             Mfinal [21][16][4]

__device__ inline void rodrigues9(float x, float y, float z, float R[9]) {
    float n2 = x * x + y * y + z * z + 1e-8f;
    float angle = sqrtf(n2);
    float inv = 1.0f / angle;
    float ax = x * inv, ay = y * inv, az = z * inv;
    float c = cosf(angle), s = sinf(angle);
    float C = 1.0f - c;
    R[0] = 1.0f - C * (ay * ay + az * az);
    R[1] = -s * az + C * ax * ay;
    R[2] = s * ay + C * ax * az;
    R[3] = s * az + C * ax * ay;
    R[4] = 1.0f - C * (ax * ax + az * az);
    R[5] = -s * ax + C * ay * az;
    R[6] = -s * ay + C * ax * az;
    R[7] = s * ax + C * ay * az;
    R[8] = 1.0f - C * (ax * ax + ay * ay);
}

// K1: NPART blocks, partial M/jt over 17 vertices each. No atomics, no memset.
__global__ __launch_bounds__(384) void prep_kernel(
    const float* __restrict__ vt, const float* __restrict__ jreg,
    const float* __restrict__ wts, float* __restrict__ Mpart) {
    int p = blockIdx.x;             // 0..NPART-1
    int t = threadIdx.x;
    int v0 = p * 17, v1 = min(v0 + 17, NV);
    float* mp = Mpart + (size_t)p * 1392;
    if (t < 336) {
        int j = t >> 4, k = t & 15;
        float m0 = 0.f, m1 = 0.f, m2 = 0.f, s = 0.f;
        for (int v = v0; v < v1; ++v) {
            float jw = jreg[v * 21 + j] * wts[v * 16 + k];
            m0 += jw * vt[v * 3 + 0];
            m1 += jw * vt[v * 3 + 1];
            m2 += jw * vt[v * 3 + 2];
            s += jw;
        }
        mp[t * 4 + 0] = m0;
        mp[t * 4 + 1] = m1;
        mp[t * 4 + 2] = m2;
        mp[t * 4 + 3] = s;
    } else if (t < 384) {           // 48 jt entries
        int o = t - 336;
        int j = o / 3, c = o - j * 3;   // j < 16
        float acc = 0.f;
        for (int v = v0; v < v1; ++v) acc += vt[v * 3 + c] * jreg[v * 21 + j];
        mp[1344 + o] = acc;
    }
}

// K2: blocks [0, nFK): FK per (batch, chain-role), euler computed inline
// (9 columns per thread). Blocks [nFK, nFK+21): lane-parallel reduce of the
// NPART M-partials into Mfinal.
__global__ __launch_bounds__(256) void fk_kernel(
    const float* __restrict__ theta, const float* __restrict__ wrist,
    const float* __restrict__ hc, const float* __restrict__ hm,
    const float* __restrict__ Mpart, float* __restrict__ wsA,
    float* __restrict__ Mfinal, int total, int nFK) {
    int blk = blockIdx.x;
    int t = threadIdx.x;
    if (blk >= nFK) {
        __shared__ float sm[256];
        int q = (blk - nFK) * 64 + (t & 63);
        int pg = t >> 6;                // 0..3
        float acc = 0.f;
#pragma unroll
        for (int u = 0; u < 16; ++u) acc += Mpart[(size_t)(pg * 16 + u) * 1392 + q];
        sm[t] = acc;
        __syncthreads();
        if (pg == 0) Mfinal[q] = sm[t] + sm[t + 64] + sm[t + 128] + sm[t + 192];
        return;
    }
    // jt reduce, lane-parallel: 192 threads = 4 p-groups x 48 entries.
    __shared__ float sred[192];
    __shared__ float sj[48];
    if (t < 192) {
        int g = t / 48, o = t - g * 48;
        float acc = 0.f;
#pragma unroll
        for (int u = 0; u < 16; ++u)
            acc += Mpart[(size_t)(g * 16 + u) * 1392 + 1344 + o];
        sred[t] = acc;
    }
    __syncthreads();
    if (t < 48) sj[t] = sred[t] + sred[48 + t] + sred[96 + t] + sred[144 + t];
    __syncthreads();

    int idx = blk * 256 + t;
    if (idx >= total) return;  // total = B*5
    int b = idx / 5, r = idx - b * 5;

    // euler columns [9r, 9r+9) for this thread only
    float e[9];
    {
        const float* th = theta + (size_t)b * 45;
        int base = 9 * r;
#pragma unroll
        for (int col = 0; col < 9; ++col) e[col] = hm[base + col];
        for (int k = 0; k < 45; ++k) {
            float tk = th[k];
            const float* hck = hc + k * 45 + base;
#pragma unroll
            for (int col = 0; col < 9; ++col) e[col] += tk * hck[col];
        }
    }

    float R[9];
    rodrigues9(wrist[b * 3 + 0], wrist[b * 3 + 1], wrist[b * 3 + 2], R);
    float J0x = sj[0], J0y = sj[1], J0z = sj[2];
    float Ap[12];
    Ap[0] = R[0]; Ap[1] = R[1]; Ap[2] = R[2]; Ap[3] = J0x;
    Ap[4] = R[3]; Ap[5] = R[4]; Ap[6] = R[5]; Ap[7] = J0y;
    Ap[8] = R[6]; Ap[9] = R[7]; Ap[10] = R[8]; Ap[11] = J0z;
    float* out = wsA + (size_t)b * 192;
    if (r == 0) {
#pragma unroll
        for (int row = 0; row < 3; ++row) {
            out[row * 4 + 0] = Ap[row * 4 + 0];
            out[row * 4 + 1] = Ap[row * 4 + 1];
            out[row * 4 + 2] = Ap[row * 4 + 2];
            out[row * 4 + 3] = Ap[row * 4 + 3] -
                (Ap[row * 4 + 0] * J0x + Ap[row * 4 + 1] * J0y + Ap[row * 4 + 2] * J0z);
        }
    }
    float px = J0x, py = J0y, pz = J0z;
#pragma unroll
    for (int s = 0; s < 3; ++s) {
        int i = r * 3 + s + 1;
        rodrigues9(e[3 * s + 0], e[3 * s + 1], e[3 * s + 2], R);
        float jx = sj[i * 3 + 0], jy = sj[i * 3 + 1], jz = sj[i * 3 + 2];
        float tx = jx - px, ty = jy - py, tz = jz - pz;
        float An[12];
#pragma unroll
        for (int row = 0; row < 3; ++row) {
            An[row * 4 + 0] = Ap[row * 4 + 0] * R[0] + Ap[row * 4 + 1] * R[3] + Ap[row * 4 + 2] * R[6];
            An[row * 4 + 1] = Ap[row * 4 + 0] * R[1] + Ap[row * 4 + 1] * R[4] + Ap[row * 4 + 2] * R[7];
            An[row * 4 + 2] = Ap[row * 4 + 0] * R[2] + Ap[row * 4 + 1] * R[5] + Ap[row * 4 + 2] * R[8];
            An[row * 4 + 3] = Ap[row * 4 + 3] + Ap[row * 4 + 0] * tx + Ap[row * 4 + 1] * ty + Ap[row * 4 + 2] * tz;
        }
        float* oi = out + i * 12;
#pragma unroll
        for (int row = 0; row < 3; ++row) {
            oi[row * 4 + 0] = An[row * 4 + 0];
            oi[row * 4 + 1] = An[row * 4 + 1];
            oi[row * 4 + 2] = An[row * 4 + 2];
            oi[row * 4 + 3] = An[row * 4 + 3] -
                (An[row * 4 + 0] * jx + An[row * 4 + 1] * jy + An[row * 4 + 2] * jz);
        }
#pragma unroll
        for (int q = 0; q < 12; ++q) Ap[q] = An[q];
        px = jx; py = jy; pz = jz;
    }
}

__device__ inline void load_w16(const float* __restrict__ wts, int v, float* w) {
    const float4* wp = (const float4*)&wts[v * 16];
    float4 q0 = wp[0], q1 = wp[1], q2 = wp[2], q3 = wp[3];
    w[0] = q0.x; w[1] = q0.y; w[2] = q0.z; w[3] = q0.w;
    w[4] = q1.x; w[5] = q1.y; w[6] = q1.z; w[7] = q1.w;
    w[8] = q2.x; w[9] = q2.y; w[10] = q2.z; w[11] = q2.w;
    w[12] = q3.x; w[13] = q3.y; w[14] = q3.z; w[15] = q3.w;
}

// K3: grid = (B/4)*5. Block = (batch-group of 4, vertex-chunk). Each thread
// owns one vertex and accumulates FOUR batches simultaneously: 4 independent
// uniform (SGPR) A-load chains overlap their latencies.
//  chunk 0..3: verts chunk*256 + t (all < 1024).
//  chunk 4: tail verts 1024..1083 + joints for the 4 batches.
__global__ __launch_bounds__(256) void verts_joints_kernel(
    const float* __restrict__ wsA, const float* __restrict__ Mfinal,
    const float* __restrict__ wts, const float* __restrict__ vtpl,
    float* __restrict__ verts, float* __restrict__ jout) {
    int bid = blockIdx.x;
    int bg = bid / 5, chunk = bid - bg * 5;
    int t = threadIdx.x;
    int b0 = bg * 4;
    const float* A0 = wsA + (size_t)(b0 + 0) * 192;
    const float* A1 = wsA + (size_t)(b0 + 1) * 192;
    const float* A2 = wsA + (size_t)(b0 + 2) * 192;
    const float* A3 = wsA + (size_t)(b0 + 3) * 192;

    if (chunk < 4) {
        int v = chunk * 256 + t;
        float w[16];
        load_w16(wts, v, w);
        float vx = vtpl[v * 3 + 0], vy = vtpl[v * 3 + 1], vz = vtpl[v * 3 + 2];
        float T0[12], T1[12], T2[12], T3[12];
#pragma unroll
        for (int q = 0; q < 12; ++q) { T0[q] = 0.f; T1[q] = 0.f; T2[q] = 0.f; T3[q] = 0.f; }
#pragma unroll
        for (int k = 0; k < 16; ++k) {
            float wk = w[k];
#pragma unroll
            for (int q = 0; q < 12; ++q) {
                T0[q] += wk * A0[k * 12 + q];
                T1[q] += wk * A1[k * 12 + q];
                T2[q] += wk * A2[k * 12 + q];
                T3[q] += wk * A3[k * 12 + q];
            }
        }
        float* o0 = verts + (size_t)(b0 + 0) * (NV * 3) + v * 3;
        float* o1 = verts + (size_t)(b0 + 1) * (NV * 3) + v * 3;
        float* o2 = verts + (size_t)(b0 + 2) * (NV * 3) + v * 3;
        float* o3 = verts + (size_t)(b0 + 3) * (NV * 3) + v * 3;
        o0[0] = T0[0] * vx + T0[1] * vy + T0[2] * vz + T0[3];
        o0[1] = T0[4] * vx + T0[5] * vy + T0[6] * vz + T0[7];
        o0[2] = T0[8] * vx + T0[9] * vy + T0[10] * vz + T0[11];
        o1[0] = T1[0] * vx + T1[1] * vy + T1[2] * vz + T1[3];
        o1[1] = T1[4] * vx + T1[5] * vy + T1[6] * vz + T1[7];
        o1[2] = T1[8] * vx + T1[9] * vy + T1[10] * vz + T1[11];
        o2[0] = T2[0] * vx + T2[1] * vy + T2[2] * vz + T2[3];
        o2[1] = T2[4] * vx + T2[5] * vy + T2[6] * vz + T2[7];
        o2[2] = T2[8] * vx + T2[9] * vy + T2[10] * vz + T2[11];
        o3[0] = T3[0] * vx + T3[1] * vy + T3[2] * vz + T3[3];
        o3[1] = T3[4] * vx + T3[5] * vy + T3[6] * vz + T3[7];
        o3[2] = T3[8] * vx + T3[9] * vy + T3[10] * vz + T3[11];
    } else {
        // tail verts 1024..1083 (60 lanes), 4-batch interleaved
        int v = 1024 + t;
        if (v < NV) {
            float w[16];
            load_w16(wts, v, w);
            float vx = vtpl[v * 3 + 0], vy = vtpl[v * 3 + 1], vz = vtpl[v * 3 + 2];
            float T0[12], T1[12], T2[12], T3[12];
#pragma unroll
            for (int q = 0; q < 12; ++q) { T0[q] = 0.f; T1[q] = 0.f; T2[q] = 0.f; T3[q] = 0.f; }
#pragma unroll
            for (int k = 0; k < 16; ++k) {
                float wk = w[k];
#pragma unroll
                for (int q = 0; q < 12; ++q) {
                    T0[q] += wk * A0[k * 12 + q];
                    T1[q] += wk * A1[k * 12 + q];
                    T2[q] += wk * A2[k * 12 + q];
                    T3[q] += wk * A3[k * 12 + q];
                }
            }
            float* o0 = verts + (size_t)(b0 + 0) * (NV * 3) + v * 3;
            float* o1 = verts + (size_t)(b0 + 1) * (NV * 3) + v * 3;
            float* o2 = verts + (size_t)(b0 + 2) * (NV * 3) + v * 3;
            float* o3 = verts + (size_t)(b0 + 3) * (NV * 3) + v * 3;
            o0[0] = T0[0] * vx + T0[1] * vy + T0[2] * vz + T0[3];
            o0[1] = T0[4] * vx + T0[5] * vy + T0[6] * vz + T0[7];
            o0[2] = T0[8] * vx + T0[9] * vy + T0[10] * vz + T0[11];
            o1[0] = T1[0] * vx + T1[1] * vy + T1[2] * vz + T1[3];
            o1[1] = T1[4] * vx + T1[5] * vy + T1[6] * vz + T1[7];
            o1[2] = T1[8] * vx + T1[9] * vy + T1[10] * vz + T1[11];
            o2[0] = T2[0] * vx + T2[1] * vy + T2[2] * vz + T2[3];
            o2[1] = T2[4] * vx + T2[5] * vy + T2[6] * vz + T2[7];
            o2[2] = T2[8] * vx + T2[9] * vy + T2[10] * vz + T2[11];
            o3[0] = T3[0] * vx + T3[1] * vy + T3[2] * vz + T3[3];
            o3[1] = T3[4] * vx + T3[5] * vy + T3[6] * vz + T3[7];
            o3[2] = T3[8] * vx + T3[9] * vy + T3[10] * vz + T3[11];
        }
        // joints for the 4 batches: 4*63 = 252 outputs
        if (t < 252) {
            int bl = t / 63;
            int rem = t - bl * 63;
            int j = rem / 3;
            int c = rem - j * 3;
            const float* A = wsA + (size_t)(b0 + bl) * 192 + c * 4;
            const float* Mj = Mfinal + j * 64;
            float acc = 0.f;
#pragma unroll
            for (int k = 0; k < 16; ++k) {
                float4 a = *(const float4*)&A[k * 12];
                float4 m = *(const float4*)&Mj[k * 4];
                acc += a.x * m.x + a.y * m.y + a.z * m.z + a.w * m.w;
            }
            jout[(size_t)(b0 + bl) * 63 + rem] = acc;
        }
    }
}

extern "C" void kernel_launch(void* const* d_in, const int* in_sizes, int n_in,
                              void* d_out, int out_size, void* d_ws, size_t ws_size,
                              hipStream_t stream) {
    const float* theta = (const float*)d_in[1];
    const float* wrist = (const float*)d_in[2];
    const float* vtpl  = (const float*)d_in[3];
    const float* jreg  = (const float*)d_in[4];
    const float* hc    = (const float*)d_in[5];
    const float* hm    = (const float*)d_in[6];
    const float* wts   = (const float*)d_in[7];
    int B = in_sizes[1] / 45;  // 4096

    float* ws     = (float*)d_ws;
    float* wsA    = ws;                            // B*192
    float* Mpart  = ws + (size_t)B * 192;          // NPART*1392
    float* Mfinal = Mpart + (size_t)NPART * 1392;  // 1344
    float* verts  = (float*)d_out;
    float* jout   = verts + (size_t)B * NV * 3;

    prep_kernel<<<NPART, 384, 0, stream>>>(vtpl, jreg, wts, Mpart);
    int nFK = (B * 5 + 255) / 256;
    fk_kernel<<<nFK + 21, 256, 0, stream>>>(theta, wrist, hc, hm, Mpart, wsA,
                                            Mfinal, B * 5, nFK);
    verts_joints_kernel<<<(B / 4) * 5, 256, 0, stream>>>(wsA, Mfinal, wts, vtpl,
                                                         verts, jout);
}